// Round 1
// baseline (66.938 us; speedup 1.0000x reference)
//
#include <hip/hip_runtime.h>
#include <math.h>

// out[b, s, d] = x[b, s, d] + pe[s, d]
//   pe[s, d] = sin(s / 10000^(d_even/D))  for even d
//            = cos(s / 10000^((d-1)/D))   for odd d
// Each thread handles one float4 of (s, d) and loops over the batch dim,
// so the trig is computed once per 8 output float4s.

template <int NB>
__global__ __launch_bounds__(256) void pe_add_kernel(const float* __restrict__ x,
                                                     float* __restrict__ out,
                                                     int n4_per_batch) {
    int i4 = blockIdx.x * blockDim.x + threadIdx.x;   // float4 index within one batch slice
    if (i4 >= n4_per_batch) return;

    const int idx = i4 << 2;           // flat float index within [S, D]
    const int s   = idx >> 10;         // / 1024 (D = 1024)
    const int d0  = idx & 1023;        // 4-aligned

    // freq = 10000^(-j_even / D) = exp2(-j_even * log2(10000) / D)
    const float C = 13.28771237954945f / 1024.0f;     // log2(10000) / D
    const float pos = (float)s;
    const float f0 = exp2f(-(float)d0 * C);
    const float f1 = exp2f(-(float)(d0 + 2) * C);
    const float a0 = pos * f0;
    const float a1 = pos * f1;

    float s0, c0, s1, c1;
    sincosf(a0, &s0, &c0);
    sincosf(a1, &s1, &c1);

    const float4 e = make_float4(s0, c0, s1, c1);

    const float4* __restrict__ xv = (const float4*)x;
    float4* __restrict__ ov       = (float4*)out;

#pragma unroll
    for (int b = 0; b < NB; ++b) {
        const size_t off = (size_t)b * n4_per_batch + i4;
        float4 v = xv[off];
        v.x += e.x;
        v.y += e.y;
        v.z += e.z;
        v.w += e.w;
        ov[off] = v;
    }
}

// Generic fallback (dynamic batch count) — same structure.
__global__ __launch_bounds__(256) void pe_add_kernel_dyn(const float* __restrict__ x,
                                                         float* __restrict__ out,
                                                         int n4_per_batch, int nb) {
    int i4 = blockIdx.x * blockDim.x + threadIdx.x;
    if (i4 >= n4_per_batch) return;

    const int idx = i4 << 2;
    const int s   = idx >> 10;
    const int d0  = idx & 1023;

    const float C = 13.28771237954945f / 1024.0f;
    const float pos = (float)s;
    const float f0 = exp2f(-(float)d0 * C);
    const float f1 = exp2f(-(float)(d0 + 2) * C);

    float s0, c0, s1, c1;
    sincosf(pos * f0, &s0, &c0);
    sincosf(pos * f1, &s1, &c1);

    const float4 e = make_float4(s0, c0, s1, c1);

    const float4* __restrict__ xv = (const float4*)x;
    float4* __restrict__ ov       = (float4*)out;

    for (int b = 0; b < nb; ++b) {
        const size_t off = (size_t)b * n4_per_batch + i4;
        float4 v = xv[off];
        v.x += e.x;
        v.y += e.y;
        v.z += e.z;
        v.w += e.w;
        ov[off] = v;
    }
}

extern "C" void kernel_launch(void* const* d_in, const int* in_sizes, int n_in,
                              void* d_out, int out_size, void* d_ws, size_t ws_size,
                              hipStream_t stream) {
    const float* x = (const float*)d_in[0];
    float* out     = (float*)d_out;

    const int S = 4096, D = 1024;              // fixed by the reference problem
    const int per_batch = S * D;               // 4,194,304 floats
    const int total     = in_sizes[0];
    const int nb        = total / per_batch;   // 8
    const int n4        = per_batch / 4;       // 1,048,576 float4s

    const int threads = 256;
    const int blocks  = (n4 + threads - 1) / threads;  // 4096

    if (nb == 8) {
        pe_add_kernel<8><<<blocks, threads, 0, stream>>>(x, out, n4);
    } else {
        pe_add_kernel_dyn<<<blocks, threads, 0, stream>>>(x, out, n4, nb);
    }
}

// Round 3
// 42.640 us; speedup vs baseline: 1.5698x; 1.5698x over previous
//
#include <hip/hip_runtime.h>
#include <math.h>

// out[b, s, d] = x[b, s, d] + pe[s, d]
//   pe[s, d] = sin(s / 10000^(d_even/D))  for even d (cos for odd d)
// Flat streaming kernel: one float4 per thread (pure copy+add pattern),
// trig computed inline per float4 (cheap __sinf/__cosf), nontemporal
// stores so `out` doesn't evict `x` from the 256 MB L3.

#define D_MODEL   1024
#define S_TOKENS  4096
#define N4_BATCH  ((S_TOKENS * D_MODEL) / 4)   // 1<<20 float4 per batch slice

typedef float f32x4 __attribute__((ext_vector_type(4)));  // native vector: NT-store OK

__global__ __launch_bounds__(256) void pe_add_flat(const float* __restrict__ x,
                                                   float* __restrict__ out,
                                                   int n4_total) {
    const int i = blockIdx.x * blockDim.x + threadIdx.x;
    if (i >= n4_total) return;

    const int i4b = i & (N4_BATCH - 1);   // float4 index within one [S, D] slice
    const int idx = i4b << 2;             // flat float index within [S, D]
    const int s   = idx >> 10;            // / D_MODEL
    const int d0  = idx & (D_MODEL - 1);  // 4-aligned

    // freq = 10000^(-j_even/D) = exp2(-j_even * log2(10000)/D)
    const float C   = 13.28771237954945f / (float)D_MODEL;  // log2(10000)/D
    const float pos = (float)s;
    const float a0  = pos * exp2f(-(float)d0 * C);
    const float a1  = pos * exp2f(-(float)(d0 + 2) * C);

    const f32x4* __restrict__ xv = (const f32x4*)x;
    f32x4 v = xv[i];
    v.x += __sinf(a0);
    v.y += __cosf(a0);
    v.z += __sinf(a1);
    v.w += __cosf(a1);

    f32x4* __restrict__ ov = (f32x4*)out;
    __builtin_nontemporal_store(v, &ov[i]);
}

extern "C" void kernel_launch(void* const* d_in, const int* in_sizes, int n_in,
                              void* d_out, int out_size, void* d_ws, size_t ws_size,
                              hipStream_t stream) {
    const float* x = (const float*)d_in[0];
    float* out     = (float*)d_out;

    const int total = in_sizes[0];        // 8 * 4096 * 1024
    const int n4    = total / 4;          // float4 count

    const int threads = 256;
    const int blocks  = (n4 + threads - 1) / threads;  // 32768

    pe_add_flat<<<blocks, threads, 0, stream>>>(x, out, n4);
}